// Round 3
// baseline (562.138 us; speedup 1.0000x reference)
//
#include <hip/hip_runtime.h>

typedef float f32x4 __attribute__((ext_vector_type(4)));
typedef __bf16 bf16x8 __attribute__((ext_vector_type(8)));
typedef unsigned int u32x4 __attribute__((ext_vector_type(4)));
typedef unsigned int u32x2 __attribute__((ext_vector_type(2)));
typedef unsigned short u16;

#define DEV __device__ __forceinline__

DEV u16 f2bf(float f) {
    unsigned int x = __float_as_uint(f);
    x += 0x7fffu + ((x >> 16) & 1u);   // round-to-nearest-even
    return (u16)(x >> 16);
}
DEV unsigned pk2(float a, float b) {
    return (unsigned)f2bf(a) | ((unsigned)f2bf(b) << 16);
}
DEV float elu(float x) { return x > 0.f ? x : expm1f(x); }

// async global->LDS, 16B per lane. LDS dest must be linear (wave base + lane*16);
// swizzle lives in the per-lane GLOBAL source address (rule #21 / m173 pattern).
DEV void gload16(const u16* g, void* l) {
    __builtin_amdgcn_global_load_lds(
        (const __attribute__((address_space(1))) unsigned int*)g,
        (__attribute__((address_space(3))) unsigned int*)l,
        16, 0, 0);
}

constexpr float INV_M = 1.f / 16384.f;   // B*N
constexpr float EPSV  = 1e-5f;

// ---------------- one-time conversion kernels ----------------

__global__ void k_cvt_bf16(const float* __restrict__ src, u16* __restrict__ dst) {
    long i = ((long)blockIdx.x * 256 + threadIdx.x) * 8;
    f32x4 a = *(const f32x4*)(src + i);
    f32x4 b = *(const f32x4*)(src + i + 4);
    u32x4 v;
    v[0] = pk2(a[0], a[1]); v[1] = pk2(a[2], a[3]);
    v[2] = pk2(b[0], b[1]); v[3] = pk2(b[2], b[3]);
    *(u32x4*)(dst + i) = v;
}

// W_blocks [15][128][128] -> WT bf16 [15][e][d] = W[k][d][e]
__global__ void k_cvt_wt(const float* __restrict__ W, u16* __restrict__ WT) {
    int o = blockIdx.x * 256 + threadIdx.x;     // < 15*128*128
    int k = o >> 14, r = o & 16383, e = r >> 7, d = r & 127;
    WT[o] = f2bf(W[(k << 14) + (d << 7) + e]);
}

// x1 = inputs @ W1 + b1 ; x2 = 0 ; fused per-channel stats partials
__global__ __launch_bounds__(256) void k_init(
        const float* __restrict__ in, const float* __restrict__ W1,
        const float* __restrict__ b1, float* __restrict__ x1,
        float* __restrict__ x2, float* __restrict__ sp) {
    __shared__ float red[2][8][128];
    int t = threadIdx.x;
    long R = (long)blockIdx.x * 64;
    int c4 = (t & 31) * 4, rg = t >> 5;
    float w0[4], w1[4], w2[4], bb4[4];
#pragma unroll
    for (int c = 0; c < 4; ++c) {
        w0[c] = W1[c4 + c]; w1[c] = W1[128 + c4 + c]; w2[c] = W1[256 + c4 + c];
        bb4[c] = b1[c4 + c];
    }
    float s[4] = {}, q[4] = {};
    for (int i = 0; i < 8; ++i) {
        long grow = R + rg + 8 * i;
        float f0 = in[grow * 3], f1 = in[grow * 3 + 1], f2 = in[grow * 3 + 2];
        f32x4 v, z = {0.f, 0.f, 0.f, 0.f};
#pragma unroll
        for (int c = 0; c < 4; ++c) {
            float val = f0 * w0[c] + f1 * w1[c] + f2 * w2[c] + bb4[c];
            v[c] = val; s[c] += val; q[c] += val * val;
        }
        *(f32x4*)(x1 + grow * 128 + c4) = v;
        *(f32x4*)(x2 + grow * 128 + c4) = z;
    }
#pragma unroll
    for (int c = 0; c < 4; ++c) { red[0][rg][c4 + c] = s[c]; red[1][rg][c4 + c] = q[c]; }
    __syncthreads();
    if (t < 128) {
        float a = 0;
#pragma unroll
        for (int g = 0; g < 8; ++g) a += red[0][g][t];
        sp[blockIdx.x * 256 + t] = a;
    } else {
        int c = t - 128; float a = 0;
#pragma unroll
        for (int g = 0; g < 8; ++g) a += red[1][g][c];
        sp[blockIdx.x * 256 + 128 + c] = a;
    }
}

// ---------------- per-iteration kernels ----------------

// reduce 256 partials -> sc/sh (BN scale/shift with gamma,beta folded)
__global__ void k_redstats(const float* __restrict__ part, const float* __restrict__ gamma,
                           const float* __restrict__ beta, float* __restrict__ scb) {
    __shared__ float su[128], sq[128];
    int t = threadIdx.x; int c = t & 127; int q = t >> 7;
    float s = 0.f;
    for (int i = 0; i < 256; ++i) s += part[i * 256 + q * 128 + c];
    if (q == 0) su[c] = s; else sq[c] = s;
    __syncthreads();
    if (t < 128) {
        float mean = su[t] * INV_M, var = sq[t] * INV_M - mean * mean;
        float a = rsqrtf(var + EPSV) * gamma[t];
        scb[t] = a; scb[128 + t] = beta[t] - mean * a;
    }
}

// h = elu(bn(x)); hw = h @ W_k ; write hw^T bf16 [b][e][n] to hT
__global__ __launch_bounds__(256) void k_bnelu(
        const float* __restrict__ x, const float* __restrict__ scb,
        const u16* __restrict__ WTk, u16* __restrict__ hT) {
    __shared__ u16 Hs[8192];        // [64 n][128 d] swz; reused as CsT [128 e][64 n]
    __shared__ u16 Ws[16384];       // [128 e][128 d] swz
    __shared__ float sc[128], sh[128];
    int t = threadIdx.x;
    int R = blockIdx.x * 64;  int bb = R >> 10, n0 = R & 1023;
    int l = t & 63, w = t >> 6;
    int wm = w >> 1, wn = w & 1;
    int l16 = l & 15, ld16 = l >> 4;

    if (t < 128) { sc[t] = scb[t]; sh[t] = scb[128 + t]; }
    __syncthreads();

    // stage W^T swizzled (16B slots, slot ^= row&7)
    {
        const u32x4* wsrc = (const u32x4*)WTk;
#pragma unroll
        for (int i = 0; i < 8; ++i) {
            int u = t + 256 * i;            // 2048 x 16B
            int r = u >> 4, s = u & 15;
            *(u32x4*)((char*)Ws + r * 256 + ((s ^ (r & 7)) << 4)) = wsrc[u];
        }
    }
    // BN+ELU -> Hs bf16 swizzled
    {
        const float* xb = x + (long)R * 128;
#pragma unroll
        for (int i = 0; i < 8; ++i) {
            int idx = t + 256 * i;
            int row = idx >> 5, c4 = (idx & 31) * 4;
            f32x4 v = *(const f32x4*)(xb + row * 128 + c4);
            float h0 = elu(v[0] * sc[c4]     + sh[c4]);
            float h1 = elu(v[1] * sc[c4 + 1] + sh[c4 + 1]);
            float h2 = elu(v[2] * sc[c4 + 2] + sh[c4 + 2]);
            float h3 = elu(v[3] * sc[c4 + 3] + sh[c4 + 3]);
            u32x2 pw = {pk2(h0, h1), pk2(h2, h3)};
            *(u32x2*)((char*)Hs + row * 256 + ((c4 * 2) ^ ((row & 7) << 4))) = pw;
        }
    }
    __syncthreads();

    // hw = h @ W  (wave 32x64 of a 64x128 tile)
    f32x4 acc[2][4] = {};
#pragma unroll
    for (int ks = 0; ks < 4; ++ks) {
        int kb = ks * 64 + ld16 * 16;
        bf16x8 af[2], bfr[4];
#pragma unroll
        for (int m = 0; m < 2; ++m) {
            int r = wm * 32 + m * 16 + l16;
            af[m] = *(const bf16x8*)((char*)Hs + r * 256 + (kb ^ ((r & 7) << 4)));
        }
#pragma unroll
        for (int n = 0; n < 4; ++n) {
            int e = wn * 64 + n * 16 + l16;
            bfr[n] = *(const bf16x8*)((char*)Ws + e * 256 + (kb ^ ((e & 7) << 4)));
        }
#pragma unroll
        for (int m = 0; m < 2; ++m)
#pragma unroll
            for (int n = 0; n < 4; ++n)
                acc[m][n] = __builtin_amdgcn_mfma_f32_16x16x32_bf16(
                    af[m], bfr[n], acc[m][n], 0, 0, 0);
    }
    __syncthreads();   // all Hs reads done; reuse as CsT

    // acc -> CsT [e][n] bf16 swizzled (lane holds 4 consecutive n per e)
#pragma unroll
    for (int m = 0; m < 2; ++m)
#pragma unroll
        for (int n = 0; n < 4; ++n) {
            int e = wn * 64 + n * 16 + l16;
            int row0 = wm * 32 + m * 16 + ld16 * 4;
            u32x2 pw = {pk2(acc[m][n][0], acc[m][n][1]),
                        pk2(acc[m][n][2], acc[m][n][3])};
            *(u32x2*)((char*)Hs + e * 128 + ((row0 * 2) ^ ((e & 7) << 4))) = pw;
        }
    __syncthreads();

    // CsT -> global hT (unswizzled rows of 64 n), 16B stores
    {
        int e = t >> 1, sg = t & 1;
        const char* base = (const char*)Hs + e * 128;
        u16* orow = hT + ((long)(bb * 128 + e)) * 1024 + n0 + sg * 32;
#pragma unroll
        for (int u = 0; u < 4; ++u) {
            u32x4 v = *(const u32x4*)(base + ((((sg * 4 + u) * 16)) ^ ((e & 7) << 4)));
            *(u32x4*)(orow + u * 8) = v;
        }
    }
}

// agg = L @ hw^T tile (64 rows x 128 e, K=1024); xio = xio(x2_old) + agg + bias;
// fused next-iter stats partials. 3-buffer gload_lds pipeline, counted vmcnt.
__global__ __launch_bounds__(256) void k_gemm(
        const u16* __restrict__ Lb, const u16* __restrict__ hT,
        const float* __restrict__ bias, float* __restrict__ xio,
        float* __restrict__ sp) {
    __shared__ u16 As[3][4096];     // [buf][64 r x 64 k] linear-written, swz content
    __shared__ u16 Bs[3][8192];     // [buf][128 e x 64 k]
    __shared__ float red[2][8][128];

    int t = threadIdx.x;
    int bid0 = blockIdx.x;
    int wg = ((bid0 & 7) << 5) | (bid0 >> 3);   // XCD swizzle: 32 contiguous wgs per XCD
    int bb = wg >> 4, n0 = (wg & 15) << 6;
    int l = t & 63, w = t >> 6;
    int wm = w >> 1, wn = w & 1;
    int l16 = l & 15, ld16 = l >> 4;

    const u16* gA = Lb + ((long)(bb * 1024 + n0)) * 1024;
    const u16* gB = hT + (long)bb * 131072;

#define STAGE(buf, kt) do {                                                   \
        int k0_ = (kt) * 64;                                                  \
        _Pragma("unroll")                                                     \
        for (int j = 0; j < 2; ++j) {                                         \
            int u = t + 256 * j; int r = u >> 3, s = u & 7;                   \
            gload16(gA + (long)r * 1024 + k0_ + ((s ^ (r & 7)) << 3),         \
                    (char*)As[buf] + u * 16);                                 \
        }                                                                     \
        _Pragma("unroll")                                                     \
        for (int j = 0; j < 4; ++j) {                                         \
            int u = t + 256 * j; int r = u >> 3, s = u & 7;                   \
            gload16(gB + (long)r * 1024 + k0_ + ((s ^ (r & 7)) << 3),         \
                    (char*)Bs[buf] + u * 16);                                 \
        }                                                                     \
    } while (0)

    f32x4 acc[2][4] = {};

    STAGE(0, 0);
    STAGE(1, 1);
    asm volatile("s_waitcnt vmcnt(6)" ::: "memory");
    __builtin_amdgcn_s_barrier();

    for (int kt = 0; kt < 16; ++kt) {
        if (kt <= 13) STAGE((kt + 2) % 3, kt + 2);
        const char* Ab = (const char*)(As[kt % 3]);
        const char* Bb = (const char*)(Bs[kt % 3]);
#pragma unroll
        for (int ks = 0; ks < 2; ++ks) {
            int kb = ks * 64 + ld16 * 16;
            bf16x8 af[2], bfr[4];
#pragma unroll
            for (int m = 0; m < 2; ++m) {
                int r = wm * 32 + m * 16 + l16;
                af[m] = *(const bf16x8*)(Ab + r * 128 + (kb ^ ((r & 7) << 4)));
            }
#pragma unroll
            for (int n = 0; n < 4; ++n) {
                int e = wn * 64 + n * 16 + l16;
                bfr[n] = *(const bf16x8*)(Bb + e * 128 + (kb ^ ((e & 7) << 4)));
            }
#pragma unroll
            for (int m = 0; m < 2; ++m)
#pragma unroll
                for (int n = 0; n < 4; ++n)
                    acc[m][n] = __builtin_amdgcn_mfma_f32_16x16x32_bf16(
                        af[m], bfr[n], acc[m][n], 0, 0, 0);
        }
        if (kt <= 13) {
            asm volatile("s_waitcnt vmcnt(6)" ::: "memory");
            __builtin_amdgcn_s_barrier();
        } else if (kt == 14) {
            asm volatile("s_waitcnt vmcnt(0)" ::: "memory");
            __builtin_amdgcn_s_barrier();
        }
    }
#undef STAGE

    // epilogue: x1_new = x2_old + agg + bias ; stats partials for next iter
    float* dst = xio + (long)(bb * 1024 + n0) * 128;
#pragma unroll
    for (int n = 0; n < 4; ++n) {
        int e = wn * 64 + n * 16 + l16;
        float bv = bias[e];
        float sv = 0.f, qv = 0.f;
#pragma unroll
        for (int m = 0; m < 2; ++m) {
            int row0 = wm * 32 + m * 16 + ld16 * 4;
            float* dp = dst + (long)row0 * 128 + e;
#pragma unroll
            for (int j = 0; j < 4; ++j) {
                float v = dp[j * 128] + acc[m][n][j] + bv;
                dp[j * 128] = v;
                sv += v; qv += v * v;
            }
        }
        red[0][wm * 4 + ld16][e] = sv;
        red[1][wm * 4 + ld16][e] = qv;
    }
    __syncthreads();
    if (t < 128) {
        float a = 0;
#pragma unroll
        for (int g = 0; g < 8; ++g) a += red[0][g][t];
        sp[bid0 * 256 + t] = a;
    } else {
        int c = t - 128; float a = 0;
#pragma unroll
        for (int g = 0; g < 8; ++g) a += red[1][g][c];
        sp[bid0 * 256 + 128 + c] = a;
    }
}

// ---------------- final kernels ----------------

__global__ void k_redstats2(const float* __restrict__ p1, const float* __restrict__ p2,
                            const float* __restrict__ g1, const float* __restrict__ be1,
                            const float* __restrict__ g2, const float* __restrict__ be2,
                            float* __restrict__ scb2) {
    int t = threadIdx.x;           // 256
    int which = t >> 7, c = t & 127;
    const float* p = which ? p2 : p1;
    float s = 0.f, q = 0.f;
    for (int i = 0; i < 256; ++i) { s += p[i * 256 + c]; q += p[i * 256 + 128 + c]; }
    float mean = s * INV_M, var = q * INV_M - mean * mean;
    const float* g = which ? g2 : g1; const float* be = which ? be2 : be1;
    float a = rsqrtf(var + EPSV) * g[c];
    scb2[which * 256 + c] = a;
    scb2[which * 256 + 128 + c] = be[c] - mean * a;
}

__global__ void k_finalpool(const float* __restrict__ x1, const float* __restrict__ x2,
                            const float* __restrict__ scb2, const float* __restrict__ mask,
                            float* __restrict__ poolP, float* __restrict__ maskP) {
    __shared__ float sc1[128], sh1[128], sc2[128], sh2[128];
    __shared__ float red[8][128];
    __shared__ float msk[64];
    int t = threadIdx.x;
    int R = blockIdx.x * 64, bb = R >> 10, tl = (R & 1023) >> 6;
    if (t < 128) {
        sc1[t] = scb2[t];       sh1[t] = scb2[128 + t];
        sc2[t] = scb2[256 + t]; sh2[t] = scb2[384 + t];
    }
    if (t >= 128 && t < 192) msk[t - 128] = mask[bb * 1024 + (R & 1023) + (t - 128)];
    __syncthreads();
    const float* xb1 = x1 + (long)R * 128;
    const float* xb2 = x2 + (long)R * 128;
    int row0 = t >> 5, c = (t & 31) * 4;
    f32x4 accv = {0.f, 0.f, 0.f, 0.f};
    for (int i = 0; i < 8; ++i) {
        int row = row0 + 8 * i;
        f32x4 v1 = *(const f32x4*)(xb1 + row * 128 + c);
        f32x4 v2 = *(const f32x4*)(xb2 + row * 128 + c);
        float m = msk[row];
        accv[0] += elu(v1[0]*sc1[c]   + sh1[c]   + v2[0]*sc2[c]   + sh2[c])   * m;
        accv[1] += elu(v1[1]*sc1[c+1] + sh1[c+1] + v2[1]*sc2[c+1] + sh2[c+1]) * m;
        accv[2] += elu(v1[2]*sc1[c+2] + sh1[c+2] + v2[2]*sc2[c+2] + sh2[c+2]) * m;
        accv[3] += elu(v1[3]*sc1[c+3] + sh1[c+3] + v2[3]*sc2[c+3] + sh2[c+3]) * m;
    }
    red[row0][c] = accv[0]; red[row0][c+1] = accv[1];
    red[row0][c+2] = accv[2]; red[row0][c+3] = accv[3];
    __syncthreads();
    if (t < 128) {
        float s = 0;
#pragma unroll
        for (int g = 0; g < 8; ++g) s += red[g][t];
        poolP[(bb * 16 + tl) * 128 + t] = s;
    }
    if (t == 0) {
        float sm = 0;
        for (int j = 0; j < 64; ++j) sm += msk[j];
        maskP[bb * 16 + tl] = sm;
    }
}

__global__ void k_out(const float* __restrict__ poolP, const float* __restrict__ maskP,
                      const float* __restrict__ W2, const float* __restrict__ b2,
                      float* __restrict__ out) {
    int bb = blockIdx.x, t = threadIdx.x;   // 128 threads
    __shared__ float pooled[128];
    __shared__ float inv;
    float s = 0;
    for (int tl = 0; tl < 16; ++tl) s += poolP[(bb * 16 + tl) * 128 + t];
    pooled[t] = s;
    if (t == 0) {
        float sm = 0;
        for (int tl = 0; tl < 16; ++tl) sm += maskP[bb * 16 + tl];
        inv = 1.f / sm;
    }
    __syncthreads();
    float acc = 0;
    for (int d = 0; d < 128; ++d) acc += pooled[d] * W2[d * 128 + t];
    out[bb * 128 + t] = acc * inv + b2[t];
}

// ---------------- host launcher ----------------

extern "C" void kernel_launch(void* const* d_in, const int* in_sizes, int n_in,
                              void* d_out, int out_size, void* d_ws, size_t ws_size,
                              hipStream_t stream) {
    const float* inputs = (const float*)d_in[0];
    const float* L      = (const float*)d_in[1];
    const float* mask   = (const float*)d_in[2];
    const float* W1     = (const float*)d_in[3];
    const float* b1     = (const float*)d_in[4];
    const float* Wb     = (const float*)d_in[5];
    const float* bblk   = (const float*)d_in[6];
    const float* gb     = (const float*)d_in[7];
    const float* beb    = (const float*)d_in[8];
    const float* g1     = (const float*)d_in[9];
    const float* be1    = (const float*)d_in[10];
    const float* g2     = (const float*)d_in[11];
    const float* be2    = (const float*)d_in[12];
    const float* W2     = (const float*)d_in[13];
    const float* b2     = (const float*)d_in[14];
    float* out = (float*)d_out;

    char* ws = (char*)d_ws;
    u16*   Lb    = (u16*)(ws);                    // 33554432 B
    u16*   WT    = (u16*)(ws + 33554432);         // 491520
    float* xA    = (float*)(ws + 34045952);       // 8388608
    float* xB    = (float*)(ws + 42434560);       // 8388608
    u16*   hT    = (u16*)(ws + 50823168);         // 4194304
    float* SP0   = (float*)(ws + 55017472);       // 262144
    float* SP1   = (float*)(ws + 55279616);       // 262144
    float* scb   = (float*)(ws + 55541760);       // 1024
    float* scb2  = (float*)(ws + 55542784);       // 2048
    // poolP/maskP overlay the hT region (hT dead after last k_gemm)
    float* poolP = (float*)(ws + 50823168);       // 131072
    float* maskP = (float*)(ws + 50823168 + 131072);
    float* SP[2] = {SP0, SP1};

    hipLaunchKernelGGL(k_cvt_bf16, dim3(8192), dim3(256), 0, stream, L, Lb);
    hipLaunchKernelGGL(k_cvt_wt,   dim3(960),  dim3(256), 0, stream, Wb, WT);
    hipLaunchKernelGGL(k_init,     dim3(256),  dim3(256), 0, stream,
                       inputs, W1, b1, xA, xB, SP0);

    float* pa = xA; float* pb = xB;
    for (int k = 0; k < 15; ++k) {
        hipLaunchKernelGGL(k_redstats, dim3(1), dim3(256), 0, stream,
                           SP[k & 1], gb + k * 128, beb + k * 128, scb);
        hipLaunchKernelGGL(k_bnelu, dim3(256), dim3(256), 0, stream,
                           pa, scb, WT + (size_t)k * 16384, hT);
        hipLaunchKernelGGL(k_gemm, dim3(256), dim3(256), 0, stream,
                           Lb, hT, bblk + k * 128, pb, SP[(k + 1) & 1]);
        float* tmp = pa; pa = pb; pb = tmp;
    }
    hipLaunchKernelGGL(k_redstats2, dim3(1), dim3(256), 0, stream,
                       SP1, SP0, g1, be1, g2, be2, scb2);
    hipLaunchKernelGGL(k_finalpool, dim3(256), dim3(256), 0, stream,
                       pa, pb, scb2, mask, poolP, maskP);
    hipLaunchKernelGGL(k_out, dim3(16), dim3(128), 0, stream, poolP, maskP, W2, b2, out);
}

// Round 4
// 559.753 us; speedup vs baseline: 1.0043x; 1.0043x over previous
//
#include <hip/hip_runtime.h>

typedef float f32x4 __attribute__((ext_vector_type(4)));
typedef __bf16 bf16x8 __attribute__((ext_vector_type(8)));
typedef unsigned int u32x4 __attribute__((ext_vector_type(4)));
typedef unsigned int u32x2 __attribute__((ext_vector_type(2)));
typedef unsigned short u16;

#define DEV __device__ __forceinline__

DEV u16 f2bf(float f) {
    unsigned int x = __float_as_uint(f);
    x += 0x7fffu + ((x >> 16) & 1u);   // round-to-nearest-even
    return (u16)(x >> 16);
}
DEV unsigned pk2(float a, float b) {
    return (unsigned)f2bf(a) | ((unsigned)f2bf(b) << 16);
}
DEV float elu(float x) { return x > 0.f ? x : expm1f(x); }

// async global->LDS, 16B per lane. LDS dest must be linear (wave base + lane*16);
// swizzle lives in the per-lane GLOBAL source address (rule #21 / m173 pattern).
DEV void gload16(const u16* g, void* l) {
    __builtin_amdgcn_global_load_lds(
        (const __attribute__((address_space(1))) unsigned int*)g,
        (__attribute__((address_space(3))) unsigned int*)l,
        16, 0, 0);
}

constexpr float INV_M = 1.f / 16384.f;   // B*N
constexpr float EPSV  = 1e-5f;

// ---------------- one-time conversion kernels ----------------

__global__ void k_cvt_bf16(const float* __restrict__ src, u16* __restrict__ dst) {
    long i = ((long)blockIdx.x * 256 + threadIdx.x) * 8;
    f32x4 a = *(const f32x4*)(src + i);
    f32x4 b = *(const f32x4*)(src + i + 4);
    u32x4 v;
    v[0] = pk2(a[0], a[1]); v[1] = pk2(a[2], a[3]);
    v[2] = pk2(b[0], b[1]); v[3] = pk2(b[2], b[3]);
    *(u32x4*)(dst + i) = v;
}

// W_blocks [15][128][128] -> WT bf16 [15][e][d] = W[k][d][e]
__global__ void k_cvt_wt(const float* __restrict__ W, u16* __restrict__ WT) {
    int o = blockIdx.x * 256 + threadIdx.x;     // < 15*128*128
    int k = o >> 14, r = o & 16383, e = r >> 7, d = r & 127;
    WT[o] = f2bf(W[(k << 14) + (d << 7) + e]);
}

// x1 = inputs @ W1 + b1 ; x2 = 0 ; fused per-channel stats partials
__global__ __launch_bounds__(256) void k_init(
        const float* __restrict__ in, const float* __restrict__ W1,
        const float* __restrict__ b1, float* __restrict__ x1,
        float* __restrict__ x2, float* __restrict__ sp) {
    __shared__ float red[2][8][128];
    int t = threadIdx.x;
    long R = (long)blockIdx.x * 64;
    int c4 = (t & 31) * 4, rg = t >> 5;
    float w0[4], w1[4], w2[4], bb4[4];
#pragma unroll
    for (int c = 0; c < 4; ++c) {
        w0[c] = W1[c4 + c]; w1[c] = W1[128 + c4 + c]; w2[c] = W1[256 + c4 + c];
        bb4[c] = b1[c4 + c];
    }
    float s[4] = {}, q[4] = {};
    for (int i = 0; i < 8; ++i) {
        long grow = R + rg + 8 * i;
        float f0 = in[grow * 3], f1 = in[grow * 3 + 1], f2 = in[grow * 3 + 2];
        f32x4 v, z = {0.f, 0.f, 0.f, 0.f};
#pragma unroll
        for (int c = 0; c < 4; ++c) {
            float val = f0 * w0[c] + f1 * w1[c] + f2 * w2[c] + bb4[c];
            v[c] = val; s[c] += val; q[c] += val * val;
        }
        *(f32x4*)(x1 + grow * 128 + c4) = v;
        *(f32x4*)(x2 + grow * 128 + c4) = z;
    }
#pragma unroll
    for (int c = 0; c < 4; ++c) { red[0][rg][c4 + c] = s[c]; red[1][rg][c4 + c] = q[c]; }
    __syncthreads();
    if (t < 128) {
        float a = 0;
#pragma unroll
        for (int g = 0; g < 8; ++g) a += red[0][g][t];
        sp[blockIdx.x * 256 + t] = a;
    } else {
        int c = t - 128; float a = 0;
#pragma unroll
        for (int g = 0; g < 8; ++g) a += red[1][g][c];
        sp[blockIdx.x * 256 + 128 + c] = a;
    }
}

// ---------------- per-iteration kernels ----------------

// reduce 256 partials -> sc/sh (BN scale/shift with gamma,beta folded)
__global__ void k_redstats(const float* __restrict__ part, const float* __restrict__ gamma,
                           const float* __restrict__ beta, float* __restrict__ scb) {
    __shared__ float su[128], sq[128];
    int t = threadIdx.x; int c = t & 127; int q = t >> 7;
    float s = 0.f;
    for (int i = 0; i < 256; ++i) s += part[i * 256 + q * 128 + c];
    if (q == 0) su[c] = s; else sq[c] = s;
    __syncthreads();
    if (t < 128) {
        float mean = su[t] * INV_M, var = sq[t] * INV_M - mean * mean;
        float a = rsqrtf(var + EPSV) * gamma[t];
        scb[t] = a; scb[128 + t] = beta[t] - mean * a;
    }
}

// h = elu(bn(x)); hw = h @ W_k ; write hw^T bf16 [b][e][n] to hT
__global__ __launch_bounds__(256) void k_bnelu(
        const float* __restrict__ x, const float* __restrict__ scb,
        const u16* __restrict__ WTk, u16* __restrict__ hT) {
    __shared__ u16 Hs[8192];        // [64 n][128 d] swz; reused as CsT [128 e][64 n]
    __shared__ u16 Ws[16384];       // [128 e][128 d] swz
    __shared__ float sc[128], sh[128];
    int t = threadIdx.x;
    int R = blockIdx.x * 64;  int bb = R >> 10, n0 = R & 1023;
    int l = t & 63, w = t >> 6;
    int wm = w >> 1, wn = w & 1;
    int l16 = l & 15, ld16 = l >> 4;

    if (t < 128) { sc[t] = scb[t]; sh[t] = scb[128 + t]; }
    __syncthreads();

    // stage W^T swizzled (16B slots, slot ^= row&7)
    {
        const u32x4* wsrc = (const u32x4*)WTk;
#pragma unroll
        for (int i = 0; i < 8; ++i) {
            int u = t + 256 * i;            // 2048 x 16B
            int r = u >> 4, s = u & 15;
            *(u32x4*)((char*)Ws + r * 256 + ((s ^ (r & 7)) << 4)) = wsrc[u];
        }
    }
    // BN+ELU -> Hs bf16 swizzled
    {
        const float* xb = x + (long)R * 128;
#pragma unroll
        for (int i = 0; i < 8; ++i) {
            int idx = t + 256 * i;
            int row = idx >> 5, c4 = (idx & 31) * 4;
            f32x4 v = *(const f32x4*)(xb + row * 128 + c4);
            float h0 = elu(v[0] * sc[c4]     + sh[c4]);
            float h1 = elu(v[1] * sc[c4 + 1] + sh[c4 + 1]);
            float h2 = elu(v[2] * sc[c4 + 2] + sh[c4 + 2]);
            float h3 = elu(v[3] * sc[c4 + 3] + sh[c4 + 3]);
            u32x2 pw = {pk2(h0, h1), pk2(h2, h3)};
            *(u32x2*)((char*)Hs + row * 256 + ((c4 * 2) ^ ((row & 7) << 4))) = pw;
        }
    }
    __syncthreads();

    // hw = h @ W  (wave 32x64 of a 64x128 tile)
    f32x4 acc[2][4] = {};
#pragma unroll
    for (int ks = 0; ks < 4; ++ks) {
        int kb = ks * 64 + ld16 * 16;
        bf16x8 af[2], bfr[4];
#pragma unroll
        for (int m = 0; m < 2; ++m) {
            int r = wm * 32 + m * 16 + l16;
            af[m] = *(const bf16x8*)((char*)Hs + r * 256 + (kb ^ ((r & 7) << 4)));
        }
#pragma unroll
        for (int n = 0; n < 4; ++n) {
            int e = wn * 64 + n * 16 + l16;
            bfr[n] = *(const bf16x8*)((char*)Ws + e * 256 + (kb ^ ((e & 7) << 4)));
        }
#pragma unroll
        for (int m = 0; m < 2; ++m)
#pragma unroll
            for (int n = 0; n < 4; ++n)
                acc[m][n] = __builtin_amdgcn_mfma_f32_16x16x32_bf16(
                    af[m], bfr[n], acc[m][n], 0, 0, 0);
    }
    __syncthreads();   // all Hs reads done; reuse as CsT

    // acc -> CsT [e][n] bf16 swizzled (lane holds 4 consecutive n per e)
#pragma unroll
    for (int m = 0; m < 2; ++m)
#pragma unroll
        for (int n = 0; n < 4; ++n) {
            int e = wn * 64 + n * 16 + l16;
            int row0 = wm * 32 + m * 16 + ld16 * 4;
            u32x2 pw = {pk2(acc[m][n][0], acc[m][n][1]),
                        pk2(acc[m][n][2], acc[m][n][3])};
            *(u32x2*)((char*)Hs + e * 128 + ((row0 * 2) ^ ((e & 7) << 4))) = pw;
        }
    __syncthreads();

    // CsT -> global hT (unswizzled rows of 64 n), 16B stores
    {
        int e = t >> 1, sg = t & 1;
        const char* base = (const char*)Hs + e * 128;
        u16* orow = hT + ((long)(bb * 128 + e)) * 1024 + n0 + sg * 32;
#pragma unroll
        for (int u = 0; u < 4; ++u) {
            u32x4 v = *(const u32x4*)(base + ((((sg * 4 + u) * 16)) ^ ((e & 7) << 4)));
            *(u32x4*)(orow + u * 8) = v;
        }
    }
}

// agg = L @ hw^T tile (64 rows x 128 e, K=1024); xio = xio(x2_old) + agg + bias;
// fused next-iter stats partials. 3-buffer gload_lds pipeline, counted vmcnt.
__global__ __launch_bounds__(256) void k_gemm(
        const u16* __restrict__ Lb, const u16* __restrict__ hT,
        const float* __restrict__ bias, float* __restrict__ xio,
        float* __restrict__ sp) {
    __shared__ u16 As[3][4096];     // [buf][64 r x 64 k] linear-written, swz content
    __shared__ u16 Bs[3][8192];     // [buf][128 e x 64 k]
    __shared__ float red[2][8][128];

    int t = threadIdx.x;
    int bid0 = blockIdx.x;
    int wg = ((bid0 & 7) << 5) | (bid0 >> 3);   // XCD swizzle: 32 contiguous wgs per XCD
    int bb = wg >> 4, n0 = (wg & 15) << 6;
    int l = t & 63, w = t >> 6;
    int wm = w >> 1, wn = w & 1;
    int l16 = l & 15, ld16 = l >> 4;

    const u16* gA = Lb + ((long)(bb * 1024 + n0)) * 1024;
    const u16* gB = hT + (long)bb * 131072;

#define STAGE(buf, kt) do {                                                   \
        int k0_ = (kt) * 64;                                                  \
        _Pragma("unroll")                                                     \
        for (int j = 0; j < 2; ++j) {                                         \
            int u = t + 256 * j; int r = u >> 3, s = u & 7;                   \
            gload16(gA + (long)r * 1024 + k0_ + ((s ^ (r & 7)) << 3),         \
                    (char*)As[buf] + u * 16);                                 \
        }                                                                     \
        _Pragma("unroll")                                                     \
        for (int j = 0; j < 4; ++j) {                                         \
            int u = t + 256 * j; int r = u >> 3, s = u & 7;                   \
            gload16(gB + (long)r * 1024 + k0_ + ((s ^ (r & 7)) << 3),         \
                    (char*)Bs[buf] + u * 16);                                 \
        }                                                                     \
    } while (0)

    f32x4 acc[2][4] = {};

    STAGE(0, 0);
    STAGE(1, 1);
    asm volatile("s_waitcnt vmcnt(6)" ::: "memory");
    __builtin_amdgcn_s_barrier();

    for (int kt = 0; kt < 16; ++kt) {
        if (kt <= 13) STAGE((kt + 2) % 3, kt + 2);
        const char* Ab = (const char*)(As[kt % 3]);
        const char* Bb = (const char*)(Bs[kt % 3]);
#pragma unroll
        for (int ks = 0; ks < 2; ++ks) {
            int kb = ks * 64 + ld16 * 16;
            bf16x8 af[2], bfr[4];
#pragma unroll
            for (int m = 0; m < 2; ++m) {
                int r = wm * 32 + m * 16 + l16;
                af[m] = *(const bf16x8*)(Ab + r * 128 + (kb ^ ((r & 7) << 4)));
            }
#pragma unroll
            for (int n = 0; n < 4; ++n) {
                int e = wn * 64 + n * 16 + l16;
                bfr[n] = *(const bf16x8*)(Bb + e * 128 + (kb ^ ((e & 7) << 4)));
            }
#pragma unroll
            for (int m = 0; m < 2; ++m)
#pragma unroll
                for (int n = 0; n < 4; ++n)
                    acc[m][n] = __builtin_amdgcn_mfma_f32_16x16x32_bf16(
                        af[m], bfr[n], acc[m][n], 0, 0, 0);
        }
        if (kt <= 13) {
            asm volatile("s_waitcnt vmcnt(6)" ::: "memory");
            __builtin_amdgcn_s_barrier();
        } else if (kt == 14) {
            asm volatile("s_waitcnt vmcnt(0)" ::: "memory");
            __builtin_amdgcn_s_barrier();
        }
    }
#undef STAGE

    // epilogue: x1_new = x2_old + agg + bias ; stats partials for next iter
    float* dst = xio + (long)(bb * 1024 + n0) * 128;
#pragma unroll
    for (int n = 0; n < 4; ++n) {
        int e = wn * 64 + n * 16 + l16;
        float bv = bias[e];
        float sv = 0.f, qv = 0.f;
#pragma unroll
        for (int m = 0; m < 2; ++m) {
            int row0 = wm * 32 + m * 16 + ld16 * 4;
            float* dp = dst + (long)row0 * 128 + e;
#pragma unroll
            for (int j = 0; j < 4; ++j) {
                float v = dp[j * 128] + acc[m][n][j] + bv;
                dp[j * 128] = v;
                sv += v; qv += v * v;
            }
        }
        red[0][wm * 4 + ld16][e] = sv;
        red[1][wm * 4 + ld16][e] = qv;
    }
    __syncthreads();
    if (t < 128) {
        float a = 0;
#pragma unroll
        for (int g = 0; g < 8; ++g) a += red[0][g][t];
        sp[bid0 * 256 + t] = a;
    } else {
        int c = t - 128; float a = 0;
#pragma unroll
        for (int g = 0; g < 8; ++g) a += red[1][g][c];
        sp[bid0 * 256 + 128 + c] = a;
    }
}

// ---------------- final kernels ----------------

__global__ void k_redstats2(const float* __restrict__ p1, const float* __restrict__ p2,
                            const float* __restrict__ g1, const float* __restrict__ be1,
                            const float* __restrict__ g2, const float* __restrict__ be2,
                            float* __restrict__ scb2) {
    int t = threadIdx.x;           // 256
    int which = t >> 7, c = t & 127;
    const float* p = which ? p2 : p1;
    float s = 0.f, q = 0.f;
    for (int i = 0; i < 256; ++i) { s += p[i * 256 + c]; q += p[i * 256 + 128 + c]; }
    float mean = s * INV_M, var = q * INV_M - mean * mean;
    const float* g = which ? g2 : g1; const float* be = which ? be2 : be1;
    float a = rsqrtf(var + EPSV) * g[c];
    scb2[which * 256 + c] = a;
    scb2[which * 256 + 128 + c] = be[c] - mean * a;
}

__global__ void k_finalpool(const float* __restrict__ x1, const float* __restrict__ x2,
                            const float* __restrict__ scb2, const float* __restrict__ mask,
                            float* __restrict__ poolP, float* __restrict__ maskP) {
    __shared__ float sc1[128], sh1[128], sc2[128], sh2[128];
    __shared__ float red[8][128];
    __shared__ float msk[64];
    int t = threadIdx.x;
    int R = blockIdx.x * 64, bb = R >> 10, tl = (R & 1023) >> 6;
    if (t < 128) {
        sc1[t] = scb2[t];       sh1[t] = scb2[128 + t];
        sc2[t] = scb2[256 + t]; sh2[t] = scb2[384 + t];
    }
    if (t >= 128 && t < 192) msk[t - 128] = mask[bb * 1024 + (R & 1023) + (t - 128)];
    __syncthreads();
    const float* xb1 = x1 + (long)R * 128;
    const float* xb2 = x2 + (long)R * 128;
    int row0 = t >> 5, c = (t & 31) * 4;
    f32x4 accv = {0.f, 0.f, 0.f, 0.f};
    for (int i = 0; i < 8; ++i) {
        int row = row0 + 8 * i;
        f32x4 v1 = *(const f32x4*)(xb1 + row * 128 + c);
        f32x4 v2 = *(const f32x4*)(xb2 + row * 128 + c);
        float m = msk[row];
        accv[0] += elu(v1[0]*sc1[c]   + sh1[c]   + v2[0]*sc2[c]   + sh2[c])   * m;
        accv[1] += elu(v1[1]*sc1[c+1] + sh1[c+1] + v2[1]*sc2[c+1] + sh2[c+1]) * m;
        accv[2] += elu(v1[2]*sc1[c+2] + sh1[c+2] + v2[2]*sc2[c+2] + sh2[c+2]) * m;
        accv[3] += elu(v1[3]*sc1[c+3] + sh1[c+3] + v2[3]*sc2[c+3] + sh2[c+3]) * m;
    }
    red[row0][c] = accv[0]; red[row0][c+1] = accv[1];
    red[row0][c+2] = accv[2]; red[row0][c+3] = accv[3];
    __syncthreads();
    if (t < 128) {
        float s = 0;
#pragma unroll
        for (int g = 0; g < 8; ++g) s += red[g][t];
        poolP[(bb * 16 + tl) * 128 + t] = s;
    }
    if (t == 0) {
        float sm = 0;
        for (int j = 0; j < 64; ++j) sm += msk[j];
        maskP[bb * 16 + tl] = sm;
    }
}

__global__ void k_out(const float* __restrict__ poolP, const float* __restrict__ maskP,
                      const float* __restrict__ W2, const float* __restrict__ b2,
                      float* __restrict__ out) {
    int bb = blockIdx.x, t = threadIdx.x;   // 128 threads
    __shared__ float pooled[128];
    __shared__ float inv;
    float s = 0;
    for (int tl = 0; tl < 16; ++tl) s += poolP[(bb * 16 + tl) * 128 + t];
    pooled[t] = s;
    if (t == 0) {
        float sm = 0;
        for (int tl = 0; tl < 16; ++tl) sm += maskP[bb * 16 + tl];
        inv = 1.f / sm;
    }
    __syncthreads();
    float acc = 0;
    for (int d = 0; d < 128; ++d) acc += pooled[d] * W2[d * 128 + t];
    out[bb * 128 + t] = acc * inv + b2[t];
}

// ---------------- host launcher ----------------

extern "C" void kernel_launch(void* const* d_in, const int* in_sizes, int n_in,
                              void* d_out, int out_size, void* d_ws, size_t ws_size,
                              hipStream_t stream) {
    const float* inputs = (const float*)d_in[0];
    const float* L      = (const float*)d_in[1];
    const float* mask   = (const float*)d_in[2];
    const float* W1     = (const float*)d_in[3];
    const float* b1     = (const float*)d_in[4];
    const float* Wb     = (const float*)d_in[5];
    const float* bblk   = (const float*)d_in[6];
    const float* gb     = (const float*)d_in[7];
    const float* beb    = (const float*)d_in[8];
    const float* g1     = (const float*)d_in[9];
    const float* be1    = (const float*)d_in[10];
    const float* g2     = (const float*)d_in[11];
    const float* be2    = (const float*)d_in[12];
    const float* W2     = (const float*)d_in[13];
    const float* b2     = (const float*)d_in[14];
    float* out = (float*)d_out;

    char* ws = (char*)d_ws;
    u16*   Lb    = (u16*)(ws);                    // 33554432 B
    u16*   WT    = (u16*)(ws + 33554432);         // 491520
    float* xA    = (float*)(ws + 34045952);       // 8388608
    float* xB    = (float*)(ws + 42434560);       // 8388608
    u16*   hT    = (u16*)(ws + 50823168);         // 4194304
    float* SP0   = (float*)(ws + 55017472);       // 262144
    float* SP1   = (float*)(ws + 55279616);       // 262144
    float* scb   = (float*)(ws + 55541760);       // 1024
    float* scb2  = (float*)(ws + 55542784);       // 2048
    // poolP/maskP overlay the hT region (hT dead after last k_gemm)
    float* poolP = (float*)(ws + 50823168);       // 131072
    float* maskP = (float*)(ws + 50823168 + 131072);
    float* SP[2] = {SP0, SP1};

    hipLaunchKernelGGL(k_cvt_bf16, dim3(8192), dim3(256), 0, stream, L, Lb);
    hipLaunchKernelGGL(k_cvt_wt,   dim3(960),  dim3(256), 0, stream, Wb, WT);
    hipLaunchKernelGGL(k_init,     dim3(256),  dim3(256), 0, stream,
                       inputs, W1, b1, xA, xB, SP0);

    float* pa = xA; float* pb = xB;
    for (int k = 0; k < 15; ++k) {
        hipLaunchKernelGGL(k_redstats, dim3(1), dim3(256), 0, stream,
                           SP[k & 1], gb + k * 128, beb + k * 128, scb);
        hipLaunchKernelGGL(k_bnelu, dim3(256), dim3(256), 0, stream,
                           pa, scb, WT + (size_t)k * 16384, hT);
        hipLaunchKernelGGL(k_gemm, dim3(256), dim3(256), 0, stream,
                           Lb, hT, bblk + k * 128, pb, SP[(k + 1) & 1]);
        float* tmp = pa; pa = pb; pb = tmp;
    }
    hipLaunchKernelGGL(k_redstats2, dim3(1), dim3(256), 0, stream,
                       SP1, SP0, g1, be1, g2, be2, scb2);
    hipLaunchKernelGGL(k_finalpool, dim3(256), dim3(256), 0, stream,
                       pa, pb, scb2, mask, poolP, maskP);
    hipLaunchKernelGGL(k_out, dim3(16), dim3(128), 0, stream, poolP, maskP, W2, b2, out);
}

// Round 5
// 559.742 us; speedup vs baseline: 1.0043x; 1.0000x over previous
//
#include <hip/hip_runtime.h>

typedef float f32x4 __attribute__((ext_vector_type(4)));
typedef __bf16 bf16x8 __attribute__((ext_vector_type(8)));
typedef unsigned int u32x4 __attribute__((ext_vector_type(4)));
typedef unsigned int u32x2 __attribute__((ext_vector_type(2)));
typedef unsigned short u16;

#define DEV __device__ __forceinline__

DEV u16 f2bf(float f) {
    unsigned int x = __float_as_uint(f);
    x += 0x7fffu + ((x >> 16) & 1u);   // round-to-nearest-even
    return (u16)(x >> 16);
}
DEV unsigned pk2(float a, float b) {
    return (unsigned)f2bf(a) | ((unsigned)f2bf(b) << 16);
}
DEV float elu(float x) { return x > 0.f ? x : expm1f(x); }

// async global->LDS, 16B per lane. LDS dest must be linear (wave base + lane*16);
// swizzle lives in the per-lane GLOBAL source address (rule #21 / m173 pattern).
DEV void gload16(const u16* g, void* l) {
    __builtin_amdgcn_global_load_lds(
        (const __attribute__((address_space(1))) unsigned int*)g,
        (__attribute__((address_space(3))) unsigned int*)l,
        16, 0, 0);
}

constexpr float INV_M = 1.f / 16384.f;   // B*N
constexpr float EPSV  = 1e-5f;

// ---------------- one-time conversion kernels ----------------

__global__ void k_cvt_bf16(const float* __restrict__ src, u16* __restrict__ dst) {
    long i = ((long)blockIdx.x * 256 + threadIdx.x) * 8;
    f32x4 a = *(const f32x4*)(src + i);
    f32x4 b = *(const f32x4*)(src + i + 4);
    u32x4 v;
    v[0] = pk2(a[0], a[1]); v[1] = pk2(a[2], a[3]);
    v[2] = pk2(b[0], b[1]); v[3] = pk2(b[2], b[3]);
    *(u32x4*)(dst + i) = v;
}

// W_blocks [15][128][128] -> WT bf16 [15][e][d] = W[k][d][e]
__global__ void k_cvt_wt(const float* __restrict__ W, u16* __restrict__ WT) {
    int o = blockIdx.x * 256 + threadIdx.x;     // < 15*128*128
    int k = o >> 14, r = o & 16383, e = r >> 7, d = r & 127;
    WT[o] = f2bf(W[(k << 14) + (d << 7) + e]);
}

// x1 = inputs @ W1 + b1 ; x2 = 0 ; fused per-channel stats partials
__global__ __launch_bounds__(256) void k_init(
        const float* __restrict__ in, const float* __restrict__ W1,
        const float* __restrict__ b1, float* __restrict__ x1,
        float* __restrict__ x2, float* __restrict__ sp) {
    __shared__ float red[2][8][128];
    int t = threadIdx.x;
    long R = (long)blockIdx.x * 64;
    int c4 = (t & 31) * 4, rg = t >> 5;
    float w0[4], w1[4], w2[4], bb4[4];
#pragma unroll
    for (int c = 0; c < 4; ++c) {
        w0[c] = W1[c4 + c]; w1[c] = W1[128 + c4 + c]; w2[c] = W1[256 + c4 + c];
        bb4[c] = b1[c4 + c];
    }
    float s[4] = {}, q[4] = {};
    for (int i = 0; i < 8; ++i) {
        long grow = R + rg + 8 * i;
        float f0 = in[grow * 3], f1 = in[grow * 3 + 1], f2 = in[grow * 3 + 2];
        f32x4 v, z = {0.f, 0.f, 0.f, 0.f};
#pragma unroll
        for (int c = 0; c < 4; ++c) {
            float val = f0 * w0[c] + f1 * w1[c] + f2 * w2[c] + bb4[c];
            v[c] = val; s[c] += val; q[c] += val * val;
        }
        *(f32x4*)(x1 + grow * 128 + c4) = v;
        *(f32x4*)(x2 + grow * 128 + c4) = z;
    }
#pragma unroll
    for (int c = 0; c < 4; ++c) { red[0][rg][c4 + c] = s[c]; red[1][rg][c4 + c] = q[c]; }
    __syncthreads();
    if (t < 128) {
        float a = 0;
#pragma unroll
        for (int g = 0; g < 8; ++g) a += red[0][g][t];
        sp[blockIdx.x * 256 + t] = a;
    } else {
        int c = t - 128; float a = 0;
#pragma unroll
        for (int g = 0; g < 8; ++g) a += red[1][g][c];
        sp[blockIdx.x * 256 + 128 + c] = a;
    }
}

// ---------------- per-iteration kernels ----------------

// reduce 256 partials -> sc/sh (BN scale/shift with gamma,beta folded)
__global__ void k_redstats(const float* __restrict__ part, const float* __restrict__ gamma,
                           const float* __restrict__ beta, float* __restrict__ scb) {
    __shared__ float su[128], sq[128];
    int t = threadIdx.x; int c = t & 127; int q = t >> 7;
    float s = 0.f;
    for (int i = 0; i < 256; ++i) s += part[i * 256 + q * 128 + c];
    if (q == 0) su[c] = s; else sq[c] = s;
    __syncthreads();
    if (t < 128) {
        float mean = su[t] * INV_M, var = sq[t] * INV_M - mean * mean;
        float a = rsqrtf(var + EPSV) * gamma[t];
        scb[t] = a; scb[128 + t] = beta[t] - mean * a;
    }
}

// h = elu(bn(x)); hw = h @ W_k ; write hw^T bf16 [b][e][n] to hT
__global__ __launch_bounds__(256) void k_bnelu(
        const float* __restrict__ x, const float* __restrict__ scb,
        const u16* __restrict__ WTk, u16* __restrict__ hT) {
    __shared__ u16 Hs[8192];        // [64 n][128 d] swz; reused as CsT [128 e][64 n]
    __shared__ u16 Ws[16384];       // [128 e][128 d] swz
    __shared__ float sc[128], sh[128];
    int t = threadIdx.x;
    int R = blockIdx.x * 64;  int bb = R >> 10, n0 = R & 1023;
    int l = t & 63, w = t >> 6;
    int wm = w >> 1, wn = w & 1;
    int l16 = l & 15, ld16 = l >> 4;

    if (t < 128) { sc[t] = scb[t]; sh[t] = scb[128 + t]; }
    __syncthreads();

    // stage W^T swizzled (16B slots, slot ^= row&7)
    {
        const u32x4* wsrc = (const u32x4*)WTk;
#pragma unroll
        for (int i = 0; i < 8; ++i) {
            int u = t + 256 * i;            // 2048 x 16B
            int r = u >> 4, s = u & 15;
            *(u32x4*)((char*)Ws + r * 256 + ((s ^ (r & 7)) << 4)) = wsrc[u];
        }
    }
    // BN+ELU -> Hs bf16 swizzled
    {
        const float* xb = x + (long)R * 128;
#pragma unroll
        for (int i = 0; i < 8; ++i) {
            int idx = t + 256 * i;
            int row = idx >> 5, c4 = (idx & 31) * 4;
            f32x4 v = *(const f32x4*)(xb + row * 128 + c4);
            float h0 = elu(v[0] * sc[c4]     + sh[c4]);
            float h1 = elu(v[1] * sc[c4 + 1] + sh[c4 + 1]);
            float h2 = elu(v[2] * sc[c4 + 2] + sh[c4 + 2]);
            float h3 = elu(v[3] * sc[c4 + 3] + sh[c4 + 3]);
            u32x2 pw = {pk2(h0, h1), pk2(h2, h3)};
            *(u32x2*)((char*)Hs + row * 256 + ((c4 * 2) ^ ((row & 7) << 4))) = pw;
        }
    }
    __syncthreads();

    // hw = h @ W  (wave 32x64 of a 64x128 tile)
    f32x4 acc[2][4] = {};
#pragma unroll
    for (int ks = 0; ks < 4; ++ks) {
        int kb = ks * 64 + ld16 * 16;
        bf16x8 af[2], bfr[4];
#pragma unroll
        for (int m = 0; m < 2; ++m) {
            int r = wm * 32 + m * 16 + l16;
            af[m] = *(const bf16x8*)((char*)Hs + r * 256 + (kb ^ ((r & 7) << 4)));
        }
#pragma unroll
        for (int n = 0; n < 4; ++n) {
            int e = wn * 64 + n * 16 + l16;
            bfr[n] = *(const bf16x8*)((char*)Ws + e * 256 + (kb ^ ((e & 7) << 4)));
        }
#pragma unroll
        for (int m = 0; m < 2; ++m)
#pragma unroll
            for (int n = 0; n < 4; ++n)
                acc[m][n] = __builtin_amdgcn_mfma_f32_16x16x32_bf16(
                    af[m], bfr[n], acc[m][n], 0, 0, 0);
    }
    __syncthreads();   // all Hs reads done; reuse as CsT

    // acc -> CsT [e][n] bf16 swizzled (lane holds 4 consecutive n per e)
#pragma unroll
    for (int m = 0; m < 2; ++m)
#pragma unroll
        for (int n = 0; n < 4; ++n) {
            int e = wn * 64 + n * 16 + l16;
            int row0 = wm * 32 + m * 16 + ld16 * 4;
            u32x2 pw = {pk2(acc[m][n][0], acc[m][n][1]),
                        pk2(acc[m][n][2], acc[m][n][3])};
            *(u32x2*)((char*)Hs + e * 128 + ((row0 * 2) ^ ((e & 7) << 4))) = pw;
        }
    __syncthreads();

    // CsT -> global hT (unswizzled rows of 64 n), 16B stores
    {
        int e = t >> 1, sg = t & 1;
        const char* base = (const char*)Hs + e * 128;
        u16* orow = hT + ((long)(bb * 128 + e)) * 1024 + n0 + sg * 32;
#pragma unroll
        for (int u = 0; u < 4; ++u) {
            u32x4 v = *(const u32x4*)(base + ((((sg * 4 + u) * 16)) ^ ((e & 7) << 4)));
            *(u32x4*)(orow + u * 8) = v;
        }
    }
}

// agg = L @ hw^T tile (64 rows x 128 e, K=1024); xio = xio(x2_old) + agg + bias;
// fused next-iter stats partials. 3-buffer gload_lds pipeline, counted vmcnt.
__global__ __launch_bounds__(256) void k_gemm(
        const u16* __restrict__ Lb, const u16* __restrict__ hT,
        const float* __restrict__ bias, float* __restrict__ xio,
        float* __restrict__ sp) {
    __shared__ u16 As[3][4096];     // [buf][64 r x 64 k] linear-written, swz content
    __shared__ u16 Bs[3][8192];     // [buf][128 e x 64 k]
    __shared__ float red[2][8][128];

    int t = threadIdx.x;
    int bid0 = blockIdx.x;
    int wg = ((bid0 & 7) << 5) | (bid0 >> 3);   // XCD swizzle: 32 contiguous wgs per XCD
    int bb = wg >> 4, n0 = (wg & 15) << 6;
    int l = t & 63, w = t >> 6;
    int wm = w >> 1, wn = w & 1;
    int l16 = l & 15, ld16 = l >> 4;

    const u16* gA = Lb + ((long)(bb * 1024 + n0)) * 1024;
    const u16* gB = hT + (long)bb * 131072;

#define STAGE(buf, kt) do {                                                   \
        int k0_ = (kt) * 64;                                                  \
        _Pragma("unroll")                                                     \
        for (int j = 0; j < 2; ++j) {                                         \
            int u = t + 256 * j; int r = u >> 3, s = u & 7;                   \
            gload16(gA + (long)r * 1024 + k0_ + ((s ^ (r & 7)) << 3),         \
                    (char*)As[buf] + u * 16);                                 \
        }                                                                     \
        _Pragma("unroll")                                                     \
        for (int j = 0; j < 4; ++j) {                                         \
            int u = t + 256 * j; int r = u >> 3, s = u & 7;                   \
            gload16(gB + (long)r * 1024 + k0_ + ((s ^ (r & 7)) << 3),         \
                    (char*)Bs[buf] + u * 16);                                 \
        }                                                                     \
    } while (0)

    f32x4 acc[2][4] = {};

    STAGE(0, 0);
    STAGE(1, 1);
    asm volatile("s_waitcnt vmcnt(6)" ::: "memory");
    __builtin_amdgcn_s_barrier();

    for (int kt = 0; kt < 16; ++kt) {
        if (kt <= 13) STAGE((kt + 2) % 3, kt + 2);
        const char* Ab = (const char*)(As[kt % 3]);
        const char* Bb = (const char*)(Bs[kt % 3]);
#pragma unroll
        for (int ks = 0; ks < 2; ++ks) {
            int kb = ks * 64 + ld16 * 16;
            bf16x8 af[2], bfr[4];
#pragma unroll
            for (int m = 0; m < 2; ++m) {
                int r = wm * 32 + m * 16 + l16;
                af[m] = *(const bf16x8*)(Ab + r * 128 + (kb ^ ((r & 7) << 4)));
            }
#pragma unroll
            for (int n = 0; n < 4; ++n) {
                int e = wn * 64 + n * 16 + l16;
                bfr[n] = *(const bf16x8*)(Bb + e * 128 + (kb ^ ((e & 7) << 4)));
            }
#pragma unroll
            for (int m = 0; m < 2; ++m)
#pragma unroll
                for (int n = 0; n < 4; ++n)
                    acc[m][n] = __builtin_amdgcn_mfma_f32_16x16x32_bf16(
                        af[m], bfr[n], acc[m][n], 0, 0, 0);
        }
        if (kt <= 13) {
            asm volatile("s_waitcnt vmcnt(6)" ::: "memory");
            __builtin_amdgcn_s_barrier();
        } else if (kt == 14) {
            asm volatile("s_waitcnt vmcnt(0)" ::: "memory");
            __builtin_amdgcn_s_barrier();
        }
    }
#undef STAGE

    // epilogue: x1_new = x2_old + agg + bias ; stats partials for next iter
    float* dst = xio + (long)(bb * 1024 + n0) * 128;
#pragma unroll
    for (int n = 0; n < 4; ++n) {
        int e = wn * 64 + n * 16 + l16;
        float bv = bias[e];
        float sv = 0.f, qv = 0.f;
#pragma unroll
        for (int m = 0; m < 2; ++m) {
            int row0 = wm * 32 + m * 16 + ld16 * 4;
            float* dp = dst + (long)row0 * 128 + e;
#pragma unroll
            for (int j = 0; j < 4; ++j) {
                float v = dp[j * 128] + acc[m][n][j] + bv;
                dp[j * 128] = v;
                sv += v; qv += v * v;
            }
        }
        red[0][wm * 4 + ld16][e] = sv;
        red[1][wm * 4 + ld16][e] = qv;
    }
    __syncthreads();
    if (t < 128) {
        float a = 0;
#pragma unroll
        for (int g = 0; g < 8; ++g) a += red[0][g][t];
        sp[bid0 * 256 + t] = a;
    } else {
        int c = t - 128; float a = 0;
#pragma unroll
        for (int g = 0; g < 8; ++g) a += red[1][g][c];
        sp[bid0 * 256 + 128 + c] = a;
    }
}

// ---------------- final kernels ----------------

__global__ void k_redstats2(const float* __restrict__ p1, const float* __restrict__ p2,
                            const float* __restrict__ g1, const float* __restrict__ be1,
                            const float* __restrict__ g2, const float* __restrict__ be2,
                            float* __restrict__ scb2) {
    int t = threadIdx.x;           // 256
    int which = t >> 7, c = t & 127;
    const float* p = which ? p2 : p1;
    float s = 0.f, q = 0.f;
    for (int i = 0; i < 256; ++i) { s += p[i * 256 + c]; q += p[i * 256 + 128 + c]; }
    float mean = s * INV_M, var = q * INV_M - mean * mean;
    const float* g = which ? g2 : g1; const float* be = which ? be2 : be1;
    float a = rsqrtf(var + EPSV) * g[c];
    scb2[which * 256 + c] = a;
    scb2[which * 256 + 128 + c] = be[c] - mean * a;
}

__global__ void k_finalpool(const float* __restrict__ x1, const float* __restrict__ x2,
                            const float* __restrict__ scb2, const float* __restrict__ mask,
                            float* __restrict__ poolP, float* __restrict__ maskP) {
    __shared__ float sc1[128], sh1[128], sc2[128], sh2[128];
    __shared__ float red[8][128];
    __shared__ float msk[64];
    int t = threadIdx.x;
    int R = blockIdx.x * 64, bb = R >> 10, tl = (R & 1023) >> 6;
    if (t < 128) {
        sc1[t] = scb2[t];       sh1[t] = scb2[128 + t];
        sc2[t] = scb2[256 + t]; sh2[t] = scb2[384 + t];
    }
    if (t >= 128 && t < 192) msk[t - 128] = mask[bb * 1024 + (R & 1023) + (t - 128)];
    __syncthreads();
    const float* xb1 = x1 + (long)R * 128;
    const float* xb2 = x2 + (long)R * 128;
    int row0 = t >> 5, c = (t & 31) * 4;
    f32x4 accv = {0.f, 0.f, 0.f, 0.f};
    for (int i = 0; i < 8; ++i) {
        int row = row0 + 8 * i;
        f32x4 v1 = *(const f32x4*)(xb1 + row * 128 + c);
        f32x4 v2 = *(const f32x4*)(xb2 + row * 128 + c);
        float m = msk[row];
        accv[0] += elu(v1[0]*sc1[c]   + sh1[c]   + v2[0]*sc2[c]   + sh2[c])   * m;
        accv[1] += elu(v1[1]*sc1[c+1] + sh1[c+1] + v2[1]*sc2[c+1] + sh2[c+1]) * m;
        accv[2] += elu(v1[2]*sc1[c+2] + sh1[c+2] + v2[2]*sc2[c+2] + sh2[c+2]) * m;
        accv[3] += elu(v1[3]*sc1[c+3] + sh1[c+3] + v2[3]*sc2[c+3] + sh2[c+3]) * m;
    }
    red[row0][c] = accv[0]; red[row0][c+1] = accv[1];
    red[row0][c+2] = accv[2]; red[row0][c+3] = accv[3];
    __syncthreads();
    if (t < 128) {
        float s = 0;
#pragma unroll
        for (int g = 0; g < 8; ++g) s += red[g][t];
        poolP[(bb * 16 + tl) * 128 + t] = s;
    }
    if (t == 0) {
        float sm = 0;
        for (int j = 0; j < 64; ++j) sm += msk[j];
        maskP[bb * 16 + tl] = sm;
    }
}

__global__ void k_out(const float* __restrict__ poolP, const float* __restrict__ maskP,
                      const float* __restrict__ W2, const float* __restrict__ b2,
                      float* __restrict__ out) {
    int bb = blockIdx.x, t = threadIdx.x;   // 128 threads
    __shared__ float pooled[128];
    __shared__ float inv;
    float s = 0;
    for (int tl = 0; tl < 16; ++tl) s += poolP[(bb * 16 + tl) * 128 + t];
    pooled[t] = s;
    if (t == 0) {
        float sm = 0;
        for (int tl = 0; tl < 16; ++tl) sm += maskP[bb * 16 + tl];
        inv = 1.f / sm;
    }
    __syncthreads();
    float acc = 0;
    for (int d = 0; d < 128; ++d) acc += pooled[d] * W2[d * 128 + t];
    out[bb * 128 + t] = acc * inv + b2[t];
}

// ---------------- host launcher ----------------

extern "C" void kernel_launch(void* const* d_in, const int* in_sizes, int n_in,
                              void* d_out, int out_size, void* d_ws, size_t ws_size,
                              hipStream_t stream) {
    const float* inputs = (const float*)d_in[0];
    const float* L      = (const float*)d_in[1];
    const float* mask   = (const float*)d_in[2];
    const float* W1     = (const float*)d_in[3];
    const float* b1     = (const float*)d_in[4];
    const float* Wb     = (const float*)d_in[5];
    const float* bblk   = (const float*)d_in[6];
    const float* gb     = (const float*)d_in[7];
    const float* beb    = (const float*)d_in[8];
    const float* g1     = (const float*)d_in[9];
    const float* be1    = (const float*)d_in[10];
    const float* g2     = (const float*)d_in[11];
    const float* be2    = (const float*)d_in[12];
    const float* W2     = (const float*)d_in[13];
    const float* b2     = (const float*)d_in[14];
    float* out = (float*)d_out;

    char* ws = (char*)d_ws;
    u16*   Lb    = (u16*)(ws);                    // 33554432 B
    u16*   WT    = (u16*)(ws + 33554432);         // 491520
    float* xA    = (float*)(ws + 34045952);       // 8388608
    float* xB    = (float*)(ws + 42434560);       // 8388608
    u16*   hT    = (u16*)(ws + 50823168);         // 4194304
    float* SP0   = (float*)(ws + 55017472);       // 262144
    float* SP1   = (float*)(ws + 55279616);       // 262144
    float* scb   = (float*)(ws + 55541760);       // 1024
    float* scb2  = (float*)(ws + 55542784);       // 2048
    // poolP/maskP overlay the hT region (hT dead after last k_gemm)
    float* poolP = (float*)(ws + 50823168);       // 131072
    float* maskP = (float*)(ws + 50823168 + 131072);
    float* SP[2] = {SP0, SP1};

    hipLaunchKernelGGL(k_cvt_bf16, dim3(8192), dim3(256), 0, stream, L, Lb);
    hipLaunchKernelGGL(k_cvt_wt,   dim3(960),  dim3(256), 0, stream, Wb, WT);
    hipLaunchKernelGGL(k_init,     dim3(256),  dim3(256), 0, stream,
                       inputs, W1, b1, xA, xB, SP0);

    float* pa = xA; float* pb = xB;
    for (int k = 0; k < 15; ++k) {
        hipLaunchKernelGGL(k_redstats, dim3(1), dim3(256), 0, stream,
                           SP[k & 1], gb + k * 128, beb + k * 128, scb);
        hipLaunchKernelGGL(k_bnelu, dim3(256), dim3(256), 0, stream,
                           pa, scb, WT + (size_t)k * 16384, hT);
        hipLaunchKernelGGL(k_gemm, dim3(256), dim3(256), 0, stream,
                           Lb, hT, bblk + k * 128, pb, SP[(k + 1) & 1]);
        float* tmp = pa; pa = pb; pb = tmp;
    }
    hipLaunchKernelGGL(k_redstats2, dim3(1), dim3(256), 0, stream,
                       SP1, SP0, g1, be1, g2, be2, scb2);
    hipLaunchKernelGGL(k_finalpool, dim3(256), dim3(256), 0, stream,
                       pa, pb, scb2, mask, poolP, maskP);
    hipLaunchKernelGGL(k_out, dim3(16), dim3(128), 0, stream, poolP, maskP, W2, b2, out);
}

// Round 6
// 393.978 us; speedup vs baseline: 1.4268x; 1.4207x over previous
//
#include <hip/hip_runtime.h>

typedef float f32x4 __attribute__((ext_vector_type(4)));
typedef __bf16 bf16x8 __attribute__((ext_vector_type(8)));
typedef unsigned int u32x4 __attribute__((ext_vector_type(4)));
typedef unsigned int u32x2 __attribute__((ext_vector_type(2)));
typedef unsigned short u16;

#define DEV __device__ __forceinline__

DEV u16 f2bf(float f) {
    unsigned int x = __float_as_uint(f);
    x += 0x7fffu + ((x >> 16) & 1u);   // round-to-nearest-even
    return (u16)(x >> 16);
}
DEV unsigned pk2(float a, float b) {
    return (unsigned)f2bf(a) | ((unsigned)f2bf(b) << 16);
}
DEV float elu(float x) { return x > 0.f ? x : expm1f(x); }

// async global->LDS, 16B per lane. LDS dest must be linear (wave base + lane*16);
// swizzle lives in the per-lane GLOBAL source address (rule #21 / m173 pattern).
DEV void gload16(const u16* g, void* l) {
    __builtin_amdgcn_global_load_lds(
        (const __attribute__((address_space(1))) unsigned int*)g,
        (__attribute__((address_space(3))) unsigned int*)l,
        16, 0, 0);
}

constexpr float INV_M = 1.f / 16384.f;   // B*N
constexpr float EPSV  = 1e-5f;

// ---------------- one-time conversion kernels ----------------

__global__ void k_cvt_bf16(const float* __restrict__ src, u16* __restrict__ dst) {
    long i = ((long)blockIdx.x * 256 + threadIdx.x) * 8;
    f32x4 a = *(const f32x4*)(src + i);
    f32x4 b = *(const f32x4*)(src + i + 4);
    u32x4 v;
    v[0] = pk2(a[0], a[1]); v[1] = pk2(a[2], a[3]);
    v[2] = pk2(b[0], b[1]); v[3] = pk2(b[2], b[3]);
    *(u32x4*)(dst + i) = v;
}

// W_blocks [15][128][128] -> WT bf16 [15][e][d] = W[k][d][e]; also zero SP0/SP1
__global__ void k_cvt_wt(const float* __restrict__ W, u16* __restrict__ WT,
                         float* __restrict__ SP0, float* __restrict__ SP1) {
    int o = blockIdx.x * 256 + threadIdx.x;     // < 15*128*128
    int k = o >> 14, r = o & 16383, e = r >> 7, d = r & 127;
    WT[o] = f2bf(W[(k << 14) + (d << 7) + e]);
    if (blockIdx.x < 32) {
        float* z = blockIdx.x < 16 ? SP0 : SP1;
        z[(blockIdx.x & 15) * 256 + threadIdx.x] = 0.f;
    }
}

// x1 = inputs @ W1 + b1 ; x2 = 0 ; stats partials via 16-slot atomics
__global__ __launch_bounds__(256) void k_init(
        const float* __restrict__ in, const float* __restrict__ W1,
        const float* __restrict__ b1, float* __restrict__ x1,
        float* __restrict__ x2, float* __restrict__ sp) {
    __shared__ float red[2][8][128];
    int t = threadIdx.x;
    long R = (long)blockIdx.x * 64;
    int c4 = (t & 31) * 4, rg = t >> 5;
    float w0[4], w1[4], w2[4], bb4[4];
#pragma unroll
    for (int c = 0; c < 4; ++c) {
        w0[c] = W1[c4 + c]; w1[c] = W1[128 + c4 + c]; w2[c] = W1[256 + c4 + c];
        bb4[c] = b1[c4 + c];
    }
    float s[4] = {}, q[4] = {};
    for (int i = 0; i < 8; ++i) {
        long grow = R + rg + 8 * i;
        float f0 = in[grow * 3], f1 = in[grow * 3 + 1], f2 = in[grow * 3 + 2];
        f32x4 v, z = {0.f, 0.f, 0.f, 0.f};
#pragma unroll
        for (int c = 0; c < 4; ++c) {
            float val = f0 * w0[c] + f1 * w1[c] + f2 * w2[c] + bb4[c];
            v[c] = val; s[c] += val; q[c] += val * val;
        }
        *(f32x4*)(x1 + grow * 128 + c4) = v;
        *(f32x4*)(x2 + grow * 128 + c4) = z;
    }
#pragma unroll
    for (int c = 0; c < 4; ++c) { red[0][rg][c4 + c] = s[c]; red[1][rg][c4 + c] = q[c]; }
    __syncthreads();
    if (t < 128) {
        float a = 0;
#pragma unroll
        for (int g = 0; g < 8; ++g) a += red[0][g][t];
        atomicAdd(&sp[(blockIdx.x & 15) * 256 + t], a);
    } else {
        int c = t - 128; float a = 0;
#pragma unroll
        for (int g = 0; g < 8; ++g) a += red[1][g][c];
        atomicAdd(&sp[(blockIdx.x & 15) * 256 + 128 + c], a);
    }
}

// ---------------- per-iteration kernels ----------------

// stats finish (16-slot sum) + h = elu(bn(x)); hw = h @ W_k ; hw^T -> hT
__global__ __launch_bounds__(256) void k_bnelu(
        const float* __restrict__ x, const float* __restrict__ spa,
        float* __restrict__ spb_zero,
        const float* __restrict__ gamma, const float* __restrict__ beta,
        const u16* __restrict__ WTk, u16* __restrict__ hT) {
    __shared__ u16 Hs[8192];        // [64 n][128 d] swz; reused as CsT [128 e][64 n]
    __shared__ u16 Ws[16384];       // [128 e][128 d] swz
    __shared__ float st[256];
    __shared__ float sc[128], sh[128];
    int t = threadIdx.x;
    int R = blockIdx.x * 64;  int bb = R >> 10, n0 = R & 1023;
    int l = t & 63, w = t >> 6;
    int wm = w >> 1, wn = w & 1;
    int l16 = l & 15, ld16 = l >> 4;

    // finish stats: sum 16 slots per (q,channel)
    {
        float s = 0.f;
#pragma unroll
        for (int i = 0; i < 16; ++i) s += spa[i * 256 + t];
        st[t] = s;
    }
    // re-zero the other-parity partial buffer for this iteration's k_gemm
    if (blockIdx.x < 16) spb_zero[blockIdx.x * 256 + t] = 0.f;

    // stage W^T swizzled (16B slots, slot ^= row&7) — independent of stats
    {
        const u32x4* wsrc = (const u32x4*)WTk;
#pragma unroll
        for (int i = 0; i < 8; ++i) {
            int u = t + 256 * i;            // 2048 x 16B
            int r = u >> 4, sl = u & 15;
            *(u32x4*)((char*)Ws + r * 256 + ((sl ^ (r & 7)) << 4)) = wsrc[u];
        }
    }
    __syncthreads();
    if (t < 128) {
        float mean = st[t] * INV_M, var = st[128 + t] * INV_M - mean * mean;
        float a = rsqrtf(var + EPSV) * gamma[t];
        sc[t] = a; sh[t] = beta[t] - mean * a;
    }
    __syncthreads();

    // BN+ELU -> Hs bf16 swizzled
    {
        const float* xb = x + (long)R * 128;
#pragma unroll
        for (int i = 0; i < 8; ++i) {
            int idx = t + 256 * i;
            int row = idx >> 5, c4 = (idx & 31) * 4;
            f32x4 v = *(const f32x4*)(xb + row * 128 + c4);
            float h0 = elu(v[0] * sc[c4]     + sh[c4]);
            float h1 = elu(v[1] * sc[c4 + 1] + sh[c4 + 1]);
            float h2 = elu(v[2] * sc[c4 + 2] + sh[c4 + 2]);
            float h3 = elu(v[3] * sc[c4 + 3] + sh[c4 + 3]);
            u32x2 pw = {pk2(h0, h1), pk2(h2, h3)};
            *(u32x2*)((char*)Hs + row * 256 + ((c4 * 2) ^ ((row & 7) << 4))) = pw;
        }
    }
    __syncthreads();

    // hw = h @ W  (wave 32x64 of a 64x128 tile)
    f32x4 acc[2][4] = {};
#pragma unroll
    for (int ks = 0; ks < 4; ++ks) {
        int kb = ks * 64 + ld16 * 16;
        bf16x8 af[2], bfr[4];
#pragma unroll
        for (int m = 0; m < 2; ++m) {
            int r = wm * 32 + m * 16 + l16;
            af[m] = *(const bf16x8*)((char*)Hs + r * 256 + (kb ^ ((r & 7) << 4)));
        }
#pragma unroll
        for (int n = 0; n < 4; ++n) {
            int e = wn * 64 + n * 16 + l16;
            bfr[n] = *(const bf16x8*)((char*)Ws + e * 256 + (kb ^ ((e & 7) << 4)));
        }
#pragma unroll
        for (int m = 0; m < 2; ++m)
#pragma unroll
            for (int n = 0; n < 4; ++n)
                acc[m][n] = __builtin_amdgcn_mfma_f32_16x16x32_bf16(
                    af[m], bfr[n], acc[m][n], 0, 0, 0);
    }
    __syncthreads();   // all Hs reads done; reuse as CsT

    // acc -> CsT [e][n] bf16 swizzled
#pragma unroll
    for (int m = 0; m < 2; ++m)
#pragma unroll
        for (int n = 0; n < 4; ++n) {
            int e = wn * 64 + n * 16 + l16;
            int row0 = wm * 32 + m * 16 + ld16 * 4;
            u32x2 pw = {pk2(acc[m][n][0], acc[m][n][1]),
                        pk2(acc[m][n][2], acc[m][n][3])};
            *(u32x2*)((char*)Hs + e * 128 + ((row0 * 2) ^ ((e & 7) << 4))) = pw;
        }
    __syncthreads();

    // CsT -> global hT (unswizzled rows of 64 n), 16B stores
    {
        int e = t >> 1, sg = t & 1;
        const char* base = (const char*)Hs + e * 128;
        u16* orow = hT + ((long)(bb * 128 + e)) * 1024 + n0 + sg * 32;
#pragma unroll
        for (int u = 0; u < 4; ++u) {
            u32x4 v = *(const u32x4*)(base + ((((sg * 4 + u) * 16)) ^ ((e & 7) << 4)));
            *(u32x4*)(orow + u * 8) = v;
        }
    }
}

// agg = L @ hw^T (64 rows x 128 e, K=1024); xio = xio(x2_old) + agg + bias;
// fused next-iter stats partials (16-slot atomics). 512 thr / 8 waves,
// 3-buffer gload_lds pipeline with counted vmcnt(3), setprio around MFMA.
__global__ __launch_bounds__(512) void k_gemm(
        const u16* __restrict__ Lb, const u16* __restrict__ hT,
        const float* __restrict__ bias, float* __restrict__ xio,
        float* __restrict__ spb) {
    __shared__ u16 As[3][4096];     // [buf][64 r x 64 k]
    __shared__ u16 Bs[3][8192];     // [buf][128 e x 64 k]
    __shared__ float red[2][8][128];

    int t = threadIdx.x;
    int bid0 = blockIdx.x;
    int wg = ((bid0 & 7) << 5) | (bid0 >> 3);   // XCD swizzle: 32 contiguous wgs per XCD
    int bb = wg >> 4, n0 = (wg & 15) << 6;
    int l = t & 63, w = t >> 6;                 // 8 waves
    int wm = w >> 2, wn = w & 3;                // 2 x 4 wave grid; wave tile 32r x 32e
    int l16 = l & 15, ld16 = l >> 4;

    const u16* gA = Lb + ((long)(bb * 1024 + n0)) * 1024;
    const u16* gB = hT + (long)bb * 131072;

#define STAGE(buf, kt) do {                                                   \
        int k0_ = (kt) * 64;                                                  \
        { int u = t; int r = u >> 3, sl = u & 7;                              \
          gload16(gA + (long)r * 1024 + k0_ + ((sl ^ (r & 7)) << 3),          \
                  (char*)As[buf] + u * 16); }                                 \
        _Pragma("unroll")                                                     \
        for (int j = 0; j < 2; ++j) {                                         \
            int u = t + 512 * j; int r = u >> 3, sl = u & 7;                  \
            gload16(gB + (long)r * 1024 + k0_ + ((sl ^ (r & 7)) << 3),        \
                    (char*)Bs[buf] + u * 16);                                 \
        }                                                                     \
    } while (0)

    f32x4 acc[2][2] = {};

    STAGE(0, 0);
    STAGE(1, 1);
    asm volatile("s_waitcnt vmcnt(3)" ::: "memory");
    __builtin_amdgcn_s_barrier();

    for (int kt = 0; kt < 16; ++kt) {
        if (kt <= 13) STAGE((kt + 2) % 3, kt + 2);
        const char* Ab = (const char*)(As[kt % 3]);
        const char* Bb = (const char*)(Bs[kt % 3]);
        __builtin_amdgcn_s_setprio(1);
#pragma unroll
        for (int ks = 0; ks < 2; ++ks) {
            int kb = ks * 64 + ld16 * 16;
            bf16x8 af[2], bfr[2];
#pragma unroll
            for (int m = 0; m < 2; ++m) {
                int r = wm * 32 + m * 16 + l16;
                af[m] = *(const bf16x8*)(Ab + r * 128 + (kb ^ ((r & 7) << 4)));
            }
#pragma unroll
            for (int n = 0; n < 2; ++n) {
                int e = wn * 32 + n * 16 + l16;
                bfr[n] = *(const bf16x8*)(Bb + e * 128 + (kb ^ ((e & 7) << 4)));
            }
#pragma unroll
            for (int m = 0; m < 2; ++m)
#pragma unroll
                for (int n = 0; n < 2; ++n)
                    acc[m][n] = __builtin_amdgcn_mfma_f32_16x16x32_bf16(
                        af[m], bfr[n], acc[m][n], 0, 0, 0);
        }
        __builtin_amdgcn_s_setprio(0);
        if (kt <= 13) {
            asm volatile("s_waitcnt vmcnt(3)" ::: "memory");
            __builtin_amdgcn_s_barrier();
        } else if (kt == 14) {
            asm volatile("s_waitcnt vmcnt(0)" ::: "memory");
            __builtin_amdgcn_s_barrier();
        }
    }
#undef STAGE

    // epilogue: x1_new = x2_old + agg + bias ; stats partials
    float* dst = xio + (long)(bb * 1024 + n0) * 128;
#pragma unroll
    for (int n = 0; n < 2; ++n) {
        int e = wn * 32 + n * 16 + l16;
        float bv = bias[e];
        float sv = 0.f, qv = 0.f;
#pragma unroll
        for (int m = 0; m < 2; ++m) {
            int row0 = wm * 32 + m * 16 + ld16 * 4;
            float* dp = dst + (long)row0 * 128 + e;
#pragma unroll
            for (int j = 0; j < 4; ++j) {
                float v = dp[j * 128] + acc[m][n][j] + bv;
                dp[j * 128] = v;
                sv += v; qv += v * v;
            }
        }
        red[0][wm * 4 + ld16][e] = sv;
        red[1][wm * 4 + ld16][e] = qv;
    }
    __syncthreads();
    if (t < 128) {
        float a = 0;
#pragma unroll
        for (int g = 0; g < 8; ++g) a += red[0][g][t];
        atomicAdd(&spb[(bid0 & 15) * 256 + t], a);
    } else if (t < 256) {
        int c = t - 128; float a = 0;
#pragma unroll
        for (int g = 0; g < 8; ++g) a += red[1][g][c];
        atomicAdd(&spb[(bid0 & 15) * 256 + 128 + c], a);
    }
}

// ---------------- final kernels ----------------

__global__ void k_redstats2(const float* __restrict__ sp1, const float* __restrict__ sp0,
                            const float* __restrict__ g1, const float* __restrict__ be1,
                            const float* __restrict__ g2, const float* __restrict__ be2,
                            float* __restrict__ scb2) {
    int t = threadIdx.x;           // 256
    int which = t >> 7, c = t & 127;
    const float* p = which ? sp0 : sp1;    // x1 stats in sp1, x2 stats in sp0
    float s = 0.f, q = 0.f;
#pragma unroll
    for (int i = 0; i < 16; ++i) { s += p[i * 256 + c]; q += p[i * 256 + 128 + c]; }
    float mean = s * INV_M, var = q * INV_M - mean * mean;
    const float* g = which ? g2 : g1; const float* be = which ? be2 : be1;
    float a = rsqrtf(var + EPSV) * g[c];
    scb2[which * 256 + c] = a;
    scb2[which * 256 + 128 + c] = be[c] - mean * a;
}

__global__ void k_finalpool(const float* __restrict__ x1, const float* __restrict__ x2,
                            const float* __restrict__ scb2, const float* __restrict__ mask,
                            float* __restrict__ poolP, float* __restrict__ maskP) {
    __shared__ float sc1[128], sh1[128], sc2[128], sh2[128];
    __shared__ float red[8][128];
    __shared__ float msk[64];
    int t = threadIdx.x;
    int R = blockIdx.x * 64, bb = R >> 10, tl = (R & 1023) >> 6;
    if (t < 128) {
        sc1[t] = scb2[t];       sh1[t] = scb2[128 + t];
        sc2[t] = scb2[256 + t]; sh2[t] = scb2[384 + t];
    }
    if (t >= 128 && t < 192) msk[t - 128] = mask[bb * 1024 + (R & 1023) + (t - 128)];
    __syncthreads();
    const float* xb1 = x1 + (long)R * 128;
    const float* xb2 = x2 + (long)R * 128;
    int row0 = t >> 5, c = (t & 31) * 4;
    f32x4 accv = {0.f, 0.f, 0.f, 0.f};
    for (int i = 0; i < 8; ++i) {
        int row = row0 + 8 * i;
        f32x4 v1 = *(const f32x4*)(xb1 + row * 128 + c);
        f32x4 v2 = *(const f32x4*)(xb2 + row * 128 + c);
        float m = msk[row];
        accv[0] += elu(v1[0]*sc1[c]   + sh1[c]   + v2[0]*sc2[c]   + sh2[c])   * m;
        accv[1] += elu(v1[1]*sc1[c+1] + sh1[c+1] + v2[1]*sc2[c+1] + sh2[c+1]) * m;
        accv[2] += elu(v1[2]*sc1[c+2] + sh1[c+2] + v2[2]*sc2[c+2] + sh2[c+2]) * m;
        accv[3] += elu(v1[3]*sc1[c+3] + sh1[c+3] + v2[3]*sc2[c+3] + sh2[c+3]) * m;
    }
    red[row0][c] = accv[0]; red[row0][c+1] = accv[1];
    red[row0][c+2] = accv[2]; red[row0][c+3] = accv[3];
    __syncthreads();
    if (t < 128) {
        float s = 0;
#pragma unroll
        for (int g = 0; g < 8; ++g) s += red[g][t];
        poolP[(bb * 16 + tl) * 128 + t] = s;
    }
    if (t == 0) {
        float sm = 0;
        for (int j = 0; j < 64; ++j) sm += msk[j];
        maskP[bb * 16 + tl] = sm;
    }
}

__global__ void k_out(const float* __restrict__ poolP, const float* __restrict__ maskP,
                      const float* __restrict__ W2, const float* __restrict__ b2,
                      float* __restrict__ out) {
    int bb = blockIdx.x, t = threadIdx.x;   // 128 threads
    __shared__ float pooled[128];
    __shared__ float inv;
    float s = 0;
    for (int tl = 0; tl < 16; ++tl) s += poolP[(bb * 16 + tl) * 128 + t];
    pooled[t] = s;
    if (t == 0) {
        float sm = 0;
        for (int tl = 0; tl < 16; ++tl) sm += maskP[bb * 16 + tl];
        inv = 1.f / sm;
    }
    __syncthreads();
    float acc = 0;
    for (int d = 0; d < 128; ++d) acc += pooled[d] * W2[d * 128 + t];
    out[bb * 128 + t] = acc * inv + b2[t];
}

// ---------------- host launcher ----------------

extern "C" void kernel_launch(void* const* d_in, const int* in_sizes, int n_in,
                              void* d_out, int out_size, void* d_ws, size_t ws_size,
                              hipStream_t stream) {
    const float* inputs = (const float*)d_in[0];
    const float* L      = (const float*)d_in[1];
    const float* mask   = (const float*)d_in[2];
    const float* W1     = (const float*)d_in[3];
    const float* b1     = (const float*)d_in[4];
    const float* Wb     = (const float*)d_in[5];
    const float* bblk   = (const float*)d_in[6];
    const float* gb     = (const float*)d_in[7];
    const float* beb    = (const float*)d_in[8];
    const float* g1     = (const float*)d_in[9];
    const float* be1    = (const float*)d_in[10];
    const float* g2     = (const float*)d_in[11];
    const float* be2    = (const float*)d_in[12];
    const float* W2     = (const float*)d_in[13];
    const float* b2     = (const float*)d_in[14];
    float* out = (float*)d_out;

    char* ws = (char*)d_ws;
    u16*   Lb    = (u16*)(ws);                    // 33554432 B
    u16*   WT    = (u16*)(ws + 33554432);         // 491520
    float* xA    = (float*)(ws + 34045952);       // 8388608
    float* xB    = (float*)(ws + 42434560);       // 8388608
    u16*   hT    = (u16*)(ws + 50823168);         // 4194304
    float* SP0   = (float*)(ws + 55017472);       // 16384 (16 slots x 256)
    float* SP1   = (float*)(ws + 55279616);       // 16384
    float* scb2  = (float*)(ws + 55542784);       // 2048
    // poolP/maskP overlay the hT region (hT dead after last k_gemm)
    float* poolP = (float*)(ws + 50823168);       // 131072
    float* maskP = (float*)(ws + 50823168 + 131072);
    float* SP[2] = {SP0, SP1};

    hipLaunchKernelGGL(k_cvt_bf16, dim3(8192), dim3(256), 0, stream, L, Lb);
    hipLaunchKernelGGL(k_cvt_wt,   dim3(960),  dim3(256), 0, stream, Wb, WT, SP0, SP1);
    hipLaunchKernelGGL(k_init,     dim3(256),  dim3(256), 0, stream,
                       inputs, W1, b1, xA, xB, SP0);

    float* pa = xA; float* pb = xB;
    for (int k = 0; k < 15; ++k) {
        hipLaunchKernelGGL(k_bnelu, dim3(256), dim3(256), 0, stream,
                           pa, SP[k & 1], SP[(k + 1) & 1],
                           gb + k * 128, beb + k * 128,
                           WT + (size_t)k * 16384, hT);
        hipLaunchKernelGGL(k_gemm, dim3(256), dim3(512), 0, stream,
                           Lb, hT, bblk + k * 128, pb, SP[(k + 1) & 1]);
        float* tmp = pa; pa = pb; pb = tmp;
    }
    hipLaunchKernelGGL(k_redstats2, dim3(1), dim3(256), 0, stream,
                       SP[1], SP[0], g1, be1, g2, be2, scb2);
    hipLaunchKernelGGL(k_finalpool, dim3(256), dim3(256), 0, stream,
                       pa, pb, scb2, mask, poolP, maskP);
    hipLaunchKernelGGL(k_out, dim3(16), dim3(128), 0, stream, poolP, maskP, W2, b2, out);
}